// Round 2
// 1104.415 us; speedup vs baseline: 1.1459x; 1.1459x over previous
//
#include <hip/hip_runtime.h>

// x:        [B=2, C=16, N=512, Ht=64, Wt=64] float32  (256 MB atlas)
// quad_idx: [Ho=1024, Wo=1024] int32
// tex_uv:   [Ho=1024, Wo=1024, 2] float32
// out:      [B, C, Ho, Wo] float32                    (134 MB)
#define HT 64
#define WT 64
#define NTEX 512
#define HO 1024
#define WO 1024
#define BC 32
#define SLAB (HT * WT)              // 4096 floats = 16 KB per (channel, texture)
#define NPIX (HO * WO)

// clang-native vector types (accepted by __builtin_nontemporal_load, unlike
// the HIP_vector_type wrappers)
typedef float  f32x4 __attribute__((ext_vector_type(4)));
typedef unsigned u32x2 __attribute__((ext_vector_type(2)));

// ---------------- ws layout (total 16 KiB + 8 MiB — unchanged budget) ----------
// [0, 2052)         base[513]   u32 (dense; read-only after k_scan)
// [4096, 12288)     cursor      u32 @ stride 4  (16 B/counter -> 4 per line;
//                               4x the atomic line-parallelism of dense layout)
// [16384, +8 MiB)   meta[NPIX]  uint2 {pix<<12|off, wv16<<16|wu16}
//                   first 32 KiB doubles as hist (u32 @ stride 16 = 64 B/counter,
//                   512 independent cachelines) — dead storage until k_meta runs.
#define WS_BASE   0
#define WS_CURSOR 4096
#define WS_META   16384
#define WS_HIST   16384
#define WS_NEEDED ((size_t)(8u << 20) + 16384)

// ---- K1: per-block LDS histogram of quad_idx -> padded global hist ----
__global__ __launch_bounds__(256) void k_hist(const int* __restrict__ quad_idx,
                                              unsigned* __restrict__ hist) {
    __shared__ unsigned h[NTEX];
    for (int i = threadIdx.x; i < NTEX; i += 256) h[i] = 0;
    __syncthreads();
    const int pix = blockIdx.x * 256 + threadIdx.x;
    atomicAdd(&h[quad_idx[pix]], 1u);
    __syncthreads();
    for (int i = threadIdx.x; i < NTEX; i += 256) {
        unsigned v = h[i];
        if (v) atomicAdd(&hist[i << 4], v);   // 64 B stride: one line per bin
    }
}

// ---- K2: exclusive scan of 512 bins (single block) ----
__global__ __launch_bounds__(512) void k_scan(const unsigned* __restrict__ hist,
                                              unsigned* __restrict__ base,
                                              unsigned* __restrict__ cursor) {
    __shared__ unsigned t[NTEX];
    const int i = threadIdx.x;
    const unsigned h = hist[i << 4];
    t[i] = h;
    __syncthreads();
    for (int s = 1; s < NTEX; s <<= 1) {
        unsigned v = (i >= s) ? t[i - s] : 0u;
        __syncthreads();
        t[i] += v;
        __syncthreads();
    }
    const unsigned excl = t[i] - h;
    base[i] = excl;
    cursor[i << 2] = excl;                    // 16 B stride
    if (i == NTEX - 1) base[NTEX] = t[i];
}

// ---- K3: build compacted per-bucket meta records ----
__global__ __launch_bounds__(256) void k_meta(const int* __restrict__ quad_idx,
                                              const float* __restrict__ tex_uv,
                                              unsigned* __restrict__ cursor,
                                              uint2* __restrict__ meta) {
    const int pix = blockIdx.x * 256 + threadIdx.x;
    const int n = quad_idx[pix];
    const float2 uv = reinterpret_cast<const float2*>(tex_uv)[pix];

    const float u = uv.x * (float)(WT - 1);
    const float v = uv.y * (float)(HT - 1);
    int x0 = (int)floorf(u);
    int y0 = (int)floorf(v);
    x0 = min(max(x0, 0), WT - 2);   // x1=x0+1 valid; wu=u-x0 matches reference clamp
    y0 = min(max(y0, 0), HT - 2);
    const float wu = u - (float)x0;
    const float wv = v - (float)y0;

    const unsigned off = (unsigned)(y0 * WT + x0);               // 12 bits (<=4094)
    const unsigned key = ((unsigned)pix << 12) | off;
    const unsigned wu16 = (unsigned)__float2int_rn(wu * 65535.0f);
    const unsigned wv16 = (unsigned)__float2int_rn(wv * 65535.0f);

    const unsigned rank = atomicAdd(&cursor[n << 2], 1u);        // padded counter
    meta[rank] = make_uint2(key, wu16 | (wv16 << 16));
}

// ---- K4: per-(bucket, channel) block: LDS-stage slab, resolve taps ----
// Block decode pins channel%8 to blockIdx%8 (XCD round-robin): each XCD works
// one channel at a time -> its 4 MB out-slab fits its own L2 -> the ~16
// scattered 4B writes per 64B out-line can merge before one eviction.
// All read streams (slab, meta) are NON-TEMPORAL: they have zero L2 reuse and
// must not evict the dirty, partially-filled output lines.
__global__ __launch_bounds__(256) void k_main(const float* __restrict__ x,
                                              const unsigned* __restrict__ base,
                                              const uint2* __restrict__ meta,
                                              float* __restrict__ out) {
    __shared__ float s[SLAB];

    const int b = blockIdx.x;        // 0..16383
    const int xcd = b & 7;
    const int i = b >> 3;            // 0..2047
    const int cgrp = i >> 9;         // 0..3
    const int n = i & 511;           // bucket / texture id
    const int c = cgrp * 8 + xcd;    // channel slab 0..31

    // coalesced slab load: 4096 floats as 1024 float4 (nt: stream past L2)
    const f32x4* __restrict__ slab4 =
        reinterpret_cast<const f32x4*>(x + ((size_t)c * NTEX + n) * SLAB);
    f32x4* s4 = reinterpret_cast<f32x4*>(s);
    #pragma unroll
    for (int j = 0; j < 4; ++j)
        s4[threadIdx.x + 256 * j] =
            __builtin_nontemporal_load(&slab4[threadIdx.x + 256 * j]);
    __syncthreads();

    const unsigned lo = base[n];
    const unsigned hi = base[n + 1];
    const u32x2* __restrict__ m = reinterpret_cast<const u32x2*>(meta + lo);
    const unsigned cnt = hi - lo;
    float* __restrict__ o = out + (size_t)c * NPIX;

    for (unsigned j = threadIdx.x; j < cnt; j += 256) {
        const u32x2 r = __builtin_nontemporal_load(&m[j]);
        const unsigned off = r.x & 4095u;
        const unsigned pix = r.x >> 12;
        const float wu = (float)(r.y & 65535u) * (1.0f / 65535.0f);
        const float wv = (float)(r.y >> 16) * (1.0f / 65535.0f);

        const float g00 = s[off];
        const float g01 = s[off + 1];
        const float g10 = s[off + WT];
        const float g11 = s[off + WT + 1];

        const float top = g00 + wu * (g01 - g00);
        const float bot = g10 + wu * (g11 - g10);
        o[pix] = top + wv * (bot - top);   // normal store: let L2 merge lines
    }
}

// ---- fallback (round-2 kernel) if ws too small ----
__global__ __launch_bounds__(256) void k_direct(const float* __restrict__ x,
                                                const int* __restrict__ quad_idx,
                                                const float* __restrict__ tex_uv,
                                                float* __restrict__ out) {
    const int pix = blockIdx.x * blockDim.x + threadIdx.x;
    const int chunk = blockIdx.y;
    const int n = quad_idx[pix];
    const float2 uv = reinterpret_cast<const float2*>(tex_uv)[pix];
    const float u = uv.x * (float)(WT - 1);
    const float v = uv.y * (float)(HT - 1);
    int x0 = (int)floorf(u), y0 = (int)floorf(v);
    x0 = min(max(x0, 0), WT - 2);
    y0 = min(max(y0, 0), HT - 2);
    const float wu = u - (float)x0, wv = v - (float)y0;
    const float w00 = (1.f - wu) * (1.f - wv), w01 = wu * (1.f - wv);
    const float w10 = (1.f - wu) * wv, w11 = wu * wv;
    const int off0 = n * SLAB + y0 * WT + x0, off1 = off0 + WT;
    const float* p = x + (size_t)chunk * 8 * NTEX * SLAB;
    float* o = out + (size_t)chunk * 8 * NPIX + pix;
    #pragma unroll
    for (int ch = 0; ch < 8; ++ch) {
        float2 r0, r1;
        __builtin_memcpy(&r0, p + off0, 8);
        __builtin_memcpy(&r1, p + off1, 8);
        o[0] = w00 * r0.x + w01 * r0.y + w10 * r1.x + w11 * r1.y;
        p += (size_t)NTEX * SLAB;
        o += NPIX;
    }
}

extern "C" void kernel_launch(void* const* d_in, const int* in_sizes, int n_in,
                              void* d_out, int out_size, void* d_ws, size_t ws_size,
                              hipStream_t stream) {
    const float* x        = (const float*)d_in[0];
    const int*   quad_idx = (const int*)d_in[1];
    const float* tex_uv   = (const float*)d_in[2];
    float*       out      = (float*)d_out;

    if (ws_size < WS_NEEDED) {  // ws_size constant per session -> same work every call
        dim3 grid(NPIX / 256, 4);
        k_direct<<<grid, 256, 0, stream>>>(x, quad_idx, tex_uv, out);
        return;
    }

    char* ws = (char*)d_ws;
    unsigned* base   = (unsigned*)(ws + WS_BASE);
    unsigned* cursor = (unsigned*)(ws + WS_CURSOR);
    unsigned* hist   = (unsigned*)(ws + WS_HIST);
    uint2*    meta   = (uint2*)(ws + WS_META);

    (void)hipMemsetAsync(hist, 0, NTEX * 64, stream);   // padded hist: 32 KB
    k_hist<<<NPIX / 256, 256, 0, stream>>>(quad_idx, hist);
    k_scan<<<1, 512, 0, stream>>>(hist, base, cursor);
    k_meta<<<NPIX / 256, 256, 0, stream>>>(quad_idx, tex_uv, cursor, meta);
    k_main<<<NTEX * BC, 256, 0, stream>>>(x, base, meta, out);
}

// Round 3
// 622.527 us; speedup vs baseline: 2.0328x; 1.7741x over previous
//
#include <hip/hip_runtime.h>

// x:        [B=2, C=16, N=512, Ht=64, Wt=64] float32  (256 MB atlas)
// quad_idx: [Ho=1024, Wo=1024] int32
// tex_uv:   [Ho=1024, Wo=1024, 2] float32
// out:      [B, C, Ho, Wo] float32                    (134 MB)
#define HT 64
#define WT 64
#define NTEX 512
#define HO 1024
#define WO 1024
#define NCH 32
#define SLAB (HT * WT)              // 4096 floats = 16 KB per (channel, texture)
#define NPIX (HO * WO)

typedef float    f32x4 __attribute__((ext_vector_type(4)));
typedef unsigned u32x4 __attribute__((ext_vector_type(4)));

// ---------------- ws layouts ----------------
// common:  base[513] @ 0 ; cursor @ 4096 (u32 @ 16 B stride — atomic padding)
// BIG  (>= 16K+140MB): rank_of @ 16K (4MB) ; meta @ 16K+4MB (8MB) ;
//                      compact @ 16K+12MB (128MB) ; hist overlays compact head
// SMALL(>= 16K+8MB):   meta @ 16K (8MB) ; hist overlays meta head ; no rank_of
#define WS_BASE   0
#define WS_CURSOR 4096
#define WS_T1     16384
#define MB (1u << 20)
#define WS_NEED_SMALL ((size_t)WS_T1 + 8 * (size_t)MB)
#define WS_NEED_BIG   ((size_t)WS_T1 + 140 * (size_t)MB)

// ---- K1: batched LDS histogram (4096 px/block -> ~130K global atomics) ----
#define HB_PIX 4096
__global__ __launch_bounds__(256) void k_hist(const int* __restrict__ qi,
                                              unsigned* __restrict__ hist) {
    __shared__ unsigned h[NTEX];
    for (int i = threadIdx.x; i < NTEX; i += 256) h[i] = 0;
    __syncthreads();
    const int p0 = blockIdx.x * HB_PIX;
    for (int k = threadIdx.x; k < HB_PIX; k += 256)
        atomicAdd(&h[qi[p0 + k]], 1u);
    __syncthreads();
    for (int i = threadIdx.x; i < NTEX; i += 256) {
        unsigned v = h[i];
        if (v) atomicAdd(&hist[i << 4], v);   // 64 B stride: one line per bin
    }
}

// ---- K2: exclusive scan of 512 bins (single block) ----
__global__ __launch_bounds__(512) void k_scan(const unsigned* __restrict__ hist,
                                              unsigned* __restrict__ base,
                                              unsigned* __restrict__ cursor) {
    __shared__ unsigned t[NTEX];
    const int i = threadIdx.x;
    const unsigned h = hist[i << 4];
    t[i] = h;
    __syncthreads();
    for (int s = 1; s < NTEX; s <<= 1) {
        unsigned v = (i >= s) ? t[i - s] : 0u;
        __syncthreads();
        t[i] += v;
        __syncthreads();
    }
    const unsigned excl = t[i] - h;
    base[i] = excl;
    cursor[i << 2] = excl;                    // 16 B stride
    if (i == NTEX - 1) base[NTEX] = t[i];
}

// ---- K3: block-batched rank reservation + meta build (+ rank_of for BIG) ----
// Two-phase: LDS count -> one span-reserving atomicAdd per nonzero bin ->
// LDS local placement. Global returning atomics: 1M -> ~130K.
#define MR_PIX 4096
__global__ __launch_bounds__(256) void k_meta(const int* __restrict__ qi,
                                              const float* __restrict__ uvp,
                                              unsigned* __restrict__ cursor,
                                              uint2* __restrict__ meta,
                                              unsigned* __restrict__ rank_of) {
    __shared__ unsigned lcount[NTEX];
    __shared__ unsigned lbase[NTEX];
    const int p0 = blockIdx.x * MR_PIX;

    for (int i = threadIdx.x; i < NTEX; i += 256) lcount[i] = 0;
    __syncthreads();
    for (int k = threadIdx.x; k < MR_PIX; k += 256)
        atomicAdd(&lcount[qi[p0 + k]], 1u);
    __syncthreads();
    for (int i = threadIdx.x; i < NTEX; i += 256) {
        const unsigned cnum = lcount[i];
        lbase[i] = cnum ? atomicAdd(&cursor[i << 2], cnum) : 0u;
    }
    __syncthreads();
    for (int i = threadIdx.x; i < NTEX; i += 256) lcount[i] = 0;
    __syncthreads();

    for (int k = threadIdx.x; k < MR_PIX; k += 256) {
        const int pix = p0 + k;
        const int n = qi[pix];
        const float2 uv = reinterpret_cast<const float2*>(uvp)[pix];

        const float u = uv.x * (float)(WT - 1);
        const float v = uv.y * (float)(HT - 1);
        int x0 = (int)floorf(u);
        int y0 = (int)floorf(v);
        x0 = min(max(x0, 0), WT - 2);   // x1=x0+1 valid; wu=u-x0 matches ref clamp
        y0 = min(max(y0, 0), HT - 2);
        const float wu = u - (float)x0;
        const float wv = v - (float)y0;

        const unsigned off  = (unsigned)(y0 * WT + x0);          // 12 bits
        const unsigned key  = ((unsigned)pix << 12) | off;
        const unsigned wu16 = (unsigned)__float2int_rn(wu * 65535.0f);
        const unsigned wv16 = (unsigned)__float2int_rn(wv * 65535.0f);

        const unsigned rank = lbase[n] + atomicAdd(&lcount[n], 1u);
        meta[rank] = make_uint2(key, wu16 | (wv16 << 16));
        if (rank_of) rank_of[pix] = rank;
    }
}

// ---- K4-BIG: bucketed gather -> COMPACT (coalesced NT stores, no scatter) ----
__global__ __launch_bounds__(256) void k_gather(const float* __restrict__ x,
                                                const unsigned* __restrict__ base,
                                                const uint2* __restrict__ meta,
                                                float* __restrict__ compact) {
    __shared__ float s[SLAB];

    const int b = blockIdx.x;        // 0..16383
    const int xcd = b & 7;
    const int i = b >> 3;
    const int cgrp = i >> 9;
    const int n = i & 511;
    const int c = cgrp * 8 + xcd;

    const f32x4* __restrict__ slab4 =
        reinterpret_cast<const f32x4*>(x + ((size_t)c * NTEX + n) * SLAB);
    f32x4* s4 = reinterpret_cast<f32x4*>(s);
    #pragma unroll
    for (int j = 0; j < 4; ++j)
        s4[threadIdx.x + 256 * j] = slab4[threadIdx.x + 256 * j];
    __syncthreads();

    const unsigned lo = base[n];
    const unsigned cnt = base[n + 1] - lo;
    const uint2* __restrict__ m = meta + lo;
    float* __restrict__ cc = compact + (size_t)c * NPIX + lo;

    for (unsigned j = threadIdx.x; j < cnt; j += 256) {
        const uint2 r = m[j];
        const unsigned off = r.x & 4095u;
        const float wu = (float)(r.y & 65535u) * (1.0f / 65535.0f);
        const float wv = (float)(r.y >> 16) * (1.0f / 65535.0f);

        const float g00 = s[off];
        const float g01 = s[off + 1];
        const float g10 = s[off + WT];
        const float g11 = s[off + WT + 1];

        const float top = g00 + wu * (g01 - g00);
        const float bot = g10 + wu * (g11 - g10);
        __builtin_nontemporal_store(top + wv * (bot - top), cc + j);
    }
}

// ---- K5-BIG: pixel-major scatter-read / coalesced-write permutation ----
// XCD-pinned channel: compact[c] (4 MB) is L2-resident per XCD while its
// channel window runs; scattered READS are cheap (no dirty-line eviction).
__global__ __launch_bounds__(256) void k_scatter(const unsigned* __restrict__ rank_of,
                                                 const float* __restrict__ compact,
                                                 float* __restrict__ out) {
    const int b = blockIdx.x;        // 0..32767
    const int xcd = b & 7;
    const int q = b >> 3;            // 0..4095
    const int cg = q >> 10;          // 0..3
    const int tile = q & 1023;       // 0..1023
    const int c = cg * 8 + xcd;

    const float* __restrict__ cc = compact + (size_t)c * NPIX;
    const int p0 = tile * 1024 + threadIdx.x * 4;

    const u32x4 r = *reinterpret_cast<const u32x4*>(rank_of + p0);
    f32x4 v;
    v.x = cc[r.x];
    v.y = cc[r.y];
    v.z = cc[r.z];
    v.w = cc[r.w];
    __builtin_nontemporal_store(v,
        reinterpret_cast<f32x4*>(out + (size_t)c * NPIX + p0));
}

// ---- K4-SMALL: round-0 scatter k_main (plain loads — NT variant regressed) ----
__global__ __launch_bounds__(256) void k_main(const float* __restrict__ x,
                                              const unsigned* __restrict__ base,
                                              const uint2* __restrict__ meta,
                                              float* __restrict__ out) {
    __shared__ float s[SLAB];

    const int b = blockIdx.x;
    const int xcd = b & 7;
    const int i = b >> 3;
    const int cgrp = i >> 9;
    const int n = i & 511;
    const int c = cgrp * 8 + xcd;

    const f32x4* __restrict__ slab4 =
        reinterpret_cast<const f32x4*>(x + ((size_t)c * NTEX + n) * SLAB);
    f32x4* s4 = reinterpret_cast<f32x4*>(s);
    #pragma unroll
    for (int j = 0; j < 4; ++j)
        s4[threadIdx.x + 256 * j] = slab4[threadIdx.x + 256 * j];
    __syncthreads();

    const unsigned lo = base[n];
    const unsigned cnt = base[n + 1] - lo;
    const uint2* __restrict__ m = meta + lo;
    float* __restrict__ o = out + (size_t)c * NPIX;

    for (unsigned j = threadIdx.x; j < cnt; j += 256) {
        const uint2 r = m[j];
        const unsigned off = r.x & 4095u;
        const unsigned pix = r.x >> 12;
        const float wu = (float)(r.y & 65535u) * (1.0f / 65535.0f);
        const float wv = (float)(r.y >> 16) * (1.0f / 65535.0f);

        const float g00 = s[off];
        const float g01 = s[off + 1];
        const float g10 = s[off + WT];
        const float g11 = s[off + WT + 1];

        const float top = g00 + wu * (g01 - g00);
        const float bot = g10 + wu * (g11 - g10);
        o[pix] = top + wv * (bot - top);
    }
}

// ---- fallback if ws tiny ----
__global__ __launch_bounds__(256) void k_direct(const float* __restrict__ x,
                                                const int* __restrict__ quad_idx,
                                                const float* __restrict__ tex_uv,
                                                float* __restrict__ out) {
    const int pix = blockIdx.x * blockDim.x + threadIdx.x;
    const int chunk = blockIdx.y;
    const int n = quad_idx[pix];
    const float2 uv = reinterpret_cast<const float2*>(tex_uv)[pix];
    const float u = uv.x * (float)(WT - 1);
    const float v = uv.y * (float)(HT - 1);
    int x0 = (int)floorf(u), y0 = (int)floorf(v);
    x0 = min(max(x0, 0), WT - 2);
    y0 = min(max(y0, 0), HT - 2);
    const float wu = u - (float)x0, wv = v - (float)y0;
    const float w00 = (1.f - wu) * (1.f - wv), w01 = wu * (1.f - wv);
    const float w10 = (1.f - wu) * wv, w11 = wu * wv;
    const int off0 = n * SLAB + y0 * WT + x0, off1 = off0 + WT;
    const float* p = x + (size_t)chunk * 8 * NTEX * SLAB;
    float* o = out + (size_t)chunk * 8 * NPIX + pix;
    #pragma unroll
    for (int ch = 0; ch < 8; ++ch) {
        float2 r0, r1;
        __builtin_memcpy(&r0, p + off0, 8);
        __builtin_memcpy(&r1, p + off1, 8);
        o[0] = w00 * r0.x + w01 * r0.y + w10 * r1.x + w11 * r1.y;
        p += (size_t)NTEX * SLAB;
        o += NPIX;
    }
}

extern "C" void kernel_launch(void* const* d_in, const int* in_sizes, int n_in,
                              void* d_out, int out_size, void* d_ws, size_t ws_size,
                              hipStream_t stream) {
    const float* x        = (const float*)d_in[0];
    const int*   quad_idx = (const int*)d_in[1];
    const float* tex_uv   = (const float*)d_in[2];
    float*       out      = (float*)d_out;
    char* ws = (char*)d_ws;

    if (ws_size >= WS_NEED_BIG) {
        unsigned* base    = (unsigned*)(ws + WS_BASE);
        unsigned* cursor  = (unsigned*)(ws + WS_CURSOR);
        unsigned* rank_of = (unsigned*)(ws + WS_T1);
        uint2*    meta    = (uint2*)(ws + WS_T1 + 4 * (size_t)MB);
        float*    compact = (float*)(ws + WS_T1 + 12 * (size_t)MB);
        unsigned* hist    = (unsigned*)(ws + WS_T1 + 12 * (size_t)MB); // overlay

        (void)hipMemsetAsync(hist, 0, NTEX * 64, stream);
        k_hist<<<NPIX / HB_PIX, 256, 0, stream>>>(quad_idx, hist);
        k_scan<<<1, 512, 0, stream>>>(hist, base, cursor);
        k_meta<<<NPIX / MR_PIX, 256, 0, stream>>>(quad_idx, tex_uv, cursor,
                                                  meta, rank_of);
        k_gather<<<NTEX * NCH, 256, 0, stream>>>(x, base, meta, compact);
        k_scatter<<<NPIX / 1024 * NCH, 256, 0, stream>>>(rank_of, compact, out);
    } else if (ws_size >= WS_NEED_SMALL) {
        unsigned* base   = (unsigned*)(ws + WS_BASE);
        unsigned* cursor = (unsigned*)(ws + WS_CURSOR);
        uint2*    meta   = (uint2*)(ws + WS_T1);
        unsigned* hist   = (unsigned*)(ws + WS_T1);   // overlay (dead pre-k_meta)

        (void)hipMemsetAsync(hist, 0, NTEX * 64, stream);
        k_hist<<<NPIX / HB_PIX, 256, 0, stream>>>(quad_idx, hist);
        k_scan<<<1, 512, 0, stream>>>(hist, base, cursor);
        k_meta<<<NPIX / MR_PIX, 256, 0, stream>>>(quad_idx, tex_uv, cursor,
                                                  meta, (unsigned*)nullptr);
        k_main<<<NTEX * NCH, 256, 0, stream>>>(x, base, meta, out);
    } else {
        dim3 grid(NPIX / 256, 4);
        k_direct<<<grid, 256, 0, stream>>>(x, quad_idx, tex_uv, out);
    }
}

// Round 4
// 554.847 us; speedup vs baseline: 2.2808x; 1.1220x over previous
//
#include <hip/hip_runtime.h>

// x:        [B=2, C=16, N=512, Ht=64, Wt=64] float32  (256 MB atlas)
// quad_idx: [Ho=1024, Wo=1024] int32
// tex_uv:   [Ho=1024, Wo=1024, 2] float32
// out:      [B, C, Ho, Wo] float32                    (134 MB)
#define HT 64
#define WT 64
#define NTEX 512
#define HO 1024
#define WO 1024
#define NCH 32
#define SLAB (HT * WT)              // 4096 floats = 16 KB per (channel, texture)
#define NPIX (HO * WO)

typedef float    f32x4 __attribute__((ext_vector_type(4)));
typedef float    f32x8 __attribute__((ext_vector_type(8)));

// ---------------- ws layouts ----------------
// common:  base[513] @ 0 ; cursor @ 4096 (u32 @ 16 B stride — atomic padding)
// BIG  (>= 16K+140MB): rank_of @ 16K (4MB) ; meta @ 16K+4MB (8MB) ;
//                      compact @ 16K+12MB (128MB, layout [cg][rank][8ch]) ;
//                      hist overlays compact head (dead until k_meta)
// SMALL(>= 16K+8MB):   meta @ 16K (8MB) ; hist overlays meta head ; no rank_of
#define WS_BASE   0
#define WS_CURSOR 4096
#define WS_T1     16384
#define MB (1u << 20)
#define WS_NEED_SMALL ((size_t)WS_T1 + 8 * (size_t)MB)
#define WS_NEED_BIG   ((size_t)WS_T1 + 140 * (size_t)MB)

// ---- K1: batched LDS histogram (4096 px/block -> ~130K global atomics) ----
#define HB_PIX 4096
__global__ __launch_bounds__(256) void k_hist(const int* __restrict__ qi,
                                              unsigned* __restrict__ hist) {
    __shared__ unsigned h[NTEX];
    for (int i = threadIdx.x; i < NTEX; i += 256) h[i] = 0;
    __syncthreads();
    const int p0 = blockIdx.x * HB_PIX;
    for (int k = threadIdx.x; k < HB_PIX; k += 256)
        atomicAdd(&h[qi[p0 + k]], 1u);
    __syncthreads();
    for (int i = threadIdx.x; i < NTEX; i += 256) {
        unsigned v = h[i];
        if (v) atomicAdd(&hist[i << 4], v);   // 64 B stride: one line per bin
    }
}

// ---- K2: exclusive scan of 512 bins (single block) ----
__global__ __launch_bounds__(512) void k_scan(const unsigned* __restrict__ hist,
                                              unsigned* __restrict__ base,
                                              unsigned* __restrict__ cursor) {
    __shared__ unsigned t[NTEX];
    const int i = threadIdx.x;
    const unsigned h = hist[i << 4];
    t[i] = h;
    __syncthreads();
    for (int s = 1; s < NTEX; s <<= 1) {
        unsigned v = (i >= s) ? t[i - s] : 0u;
        __syncthreads();
        t[i] += v;
        __syncthreads();
    }
    const unsigned excl = t[i] - h;
    base[i] = excl;
    cursor[i << 2] = excl;                    // 16 B stride
    if (i == NTEX - 1) base[NTEX] = t[i];
}

// ---- K3: block-batched rank reservation + meta build (+ rank_of for BIG) ----
#define MR_PIX 4096
__global__ __launch_bounds__(256) void k_meta(const int* __restrict__ qi,
                                              const float* __restrict__ uvp,
                                              unsigned* __restrict__ cursor,
                                              uint2* __restrict__ meta,
                                              unsigned* __restrict__ rank_of) {
    __shared__ unsigned lcount[NTEX];
    __shared__ unsigned lbase[NTEX];
    const int p0 = blockIdx.x * MR_PIX;

    for (int i = threadIdx.x; i < NTEX; i += 256) lcount[i] = 0;
    __syncthreads();
    for (int k = threadIdx.x; k < MR_PIX; k += 256)
        atomicAdd(&lcount[qi[p0 + k]], 1u);
    __syncthreads();
    for (int i = threadIdx.x; i < NTEX; i += 256) {
        const unsigned cnum = lcount[i];
        lbase[i] = cnum ? atomicAdd(&cursor[i << 2], cnum) : 0u;
    }
    __syncthreads();
    for (int i = threadIdx.x; i < NTEX; i += 256) lcount[i] = 0;
    __syncthreads();

    for (int k = threadIdx.x; k < MR_PIX; k += 256) {
        const int pix = p0 + k;
        const int n = qi[pix];
        const float2 uv = reinterpret_cast<const float2*>(uvp)[pix];

        const float u = uv.x * (float)(WT - 1);
        const float v = uv.y * (float)(HT - 1);
        int x0 = (int)floorf(u);
        int y0 = (int)floorf(v);
        x0 = min(max(x0, 0), WT - 2);   // x1=x0+1 valid; wu=u-x0 matches ref clamp
        y0 = min(max(y0, 0), HT - 2);
        const float wu = u - (float)x0;
        const float wv = v - (float)y0;

        const unsigned off  = (unsigned)(y0 * WT + x0);          // 12 bits
        const unsigned key  = ((unsigned)pix << 12) | off;
        const unsigned wu16 = (unsigned)__float2int_rn(wu * 65535.0f);
        const unsigned wv16 = (unsigned)__float2int_rn(wv * 65535.0f);

        const unsigned rank = lbase[n] + atomicAdd(&lcount[n], 1u);
        meta[rank] = make_uint2(key, wu16 | (wv16 << 16));
        if (rank_of) rank_of[pix] = rank;
    }
}

// ---- K4-BIG: (texture, 8-channel group) -> compact_cg[rank][8]  ----
// 8 slabs staged in 128 KB LDS; each record emits one contiguous 32 B NT
// store (ranks within a bucket are contiguous -> perfectly coalesced writes,
// zero cross-block line sharing). Meta read 4x total (was 32x).
__global__ __launch_bounds__(512) void k_gather8(const float* __restrict__ x,
                                                 const unsigned* __restrict__ base,
                                                 const uint2* __restrict__ meta,
                                                 float* __restrict__ compact) {
    __shared__ float s[8 * SLAB];    // 128 KB
    const int b = blockIdx.x;        // 0..2047
    const int n = b & 511;           // texture
    const int cg = b >> 9;           // channel group 0..3
    const int tid = threadIdx.x;

    #pragma unroll
    for (int ch = 0; ch < 8; ++ch) {
        const f32x4* __restrict__ src = reinterpret_cast<const f32x4*>(
            x + ((size_t)(cg * 8 + ch) * NTEX + n) * SLAB);
        f32x4* d = reinterpret_cast<f32x4*>(s + ch * SLAB);
        d[tid]       = src[tid];
        d[tid + 512] = src[tid + 512];
    }
    __syncthreads();

    const unsigned lo = base[n];
    const unsigned cnt = base[n + 1] - lo;
    const uint2* __restrict__ m = meta + lo;
    float* __restrict__ cc = compact + ((size_t)cg * NPIX + lo) * 8;

    for (unsigned j = tid; j < cnt; j += 512) {
        const uint2 r = m[j];
        const unsigned off = r.x & 4095u;
        const float wu = (float)(r.y & 65535u) * (1.0f / 65535.0f);
        const float wv = (float)(r.y >> 16) * (1.0f / 65535.0f);

        f32x8 o;
        #pragma unroll
        for (int ch = 0; ch < 8; ++ch) {
            const float* __restrict__ sc = s + ch * SLAB + off;
            const float g00 = sc[0];
            const float g01 = sc[1];
            const float g10 = sc[WT];
            const float g11 = sc[WT + 1];
            const float top = g00 + wu * (g01 - g00);
            const float bot = g10 + wu * (g11 - g10);
            o[ch] = top + wv * (bot - top);
        }
        __builtin_nontemporal_store(o,
            reinterpret_cast<f32x8*>(cc + (size_t)j * 8));
    }
}

// ---- K5-BIG: pixel-major permutation, channel-vectorized ----
// One thread = one pixel: rank_of read ONCE (was 32x), 4 x 32 B full-line
// scattered reads (was 32 x 4 B), all 32 channel values land in registers ->
// 32 coalesced NT dword stores. No LDS, no transpose needed.
__global__ __launch_bounds__(256) void k_scatter32(const unsigned* __restrict__ rank_of,
                                                   const float* __restrict__ compact,
                                                   float* __restrict__ out) {
    const int t = threadIdx.x;
    const int P = blockIdx.x * 256;
    const size_t r = (size_t)rank_of[P + t];

    f32x4 v[8];
    #pragma unroll
    for (int cg = 0; cg < 4; ++cg) {
        const f32x4* __restrict__ src = reinterpret_cast<const f32x4*>(
            compact + ((size_t)cg * NPIX + r) * 8);
        v[cg * 2]     = src[0];
        v[cg * 2 + 1] = src[1];
    }
    float* __restrict__ o = out + P + t;
    #pragma unroll
    for (int c = 0; c < 32; ++c)
        __builtin_nontemporal_store(v[c >> 2][c & 3], o + (size_t)c * NPIX);
}

// ---- K4-SMALL: round-0 scatter k_main ----
__global__ __launch_bounds__(256) void k_main(const float* __restrict__ x,
                                              const unsigned* __restrict__ base,
                                              const uint2* __restrict__ meta,
                                              float* __restrict__ out) {
    __shared__ float s[SLAB];

    const int b = blockIdx.x;
    const int xcd = b & 7;
    const int i = b >> 3;
    const int cgrp = i >> 9;
    const int n = i & 511;
    const int c = cgrp * 8 + xcd;

    const f32x4* __restrict__ slab4 =
        reinterpret_cast<const f32x4*>(x + ((size_t)c * NTEX + n) * SLAB);
    f32x4* s4 = reinterpret_cast<f32x4*>(s);
    #pragma unroll
    for (int j = 0; j < 4; ++j)
        s4[threadIdx.x + 256 * j] = slab4[threadIdx.x + 256 * j];
    __syncthreads();

    const unsigned lo = base[n];
    const unsigned cnt = base[n + 1] - lo;
    const uint2* __restrict__ m = meta + lo;
    float* __restrict__ o = out + (size_t)c * NPIX;

    for (unsigned j = threadIdx.x; j < cnt; j += 256) {
        const uint2 r = m[j];
        const unsigned off = r.x & 4095u;
        const unsigned pix = r.x >> 12;
        const float wu = (float)(r.y & 65535u) * (1.0f / 65535.0f);
        const float wv = (float)(r.y >> 16) * (1.0f / 65535.0f);

        const float g00 = s[off];
        const float g01 = s[off + 1];
        const float g10 = s[off + WT];
        const float g11 = s[off + WT + 1];

        const float top = g00 + wu * (g01 - g00);
        const float bot = g10 + wu * (g11 - g10);
        o[pix] = top + wv * (bot - top);
    }
}

// ---- fallback if ws tiny ----
__global__ __launch_bounds__(256) void k_direct(const float* __restrict__ x,
                                                const int* __restrict__ quad_idx,
                                                const float* __restrict__ tex_uv,
                                                float* __restrict__ out) {
    const int pix = blockIdx.x * blockDim.x + threadIdx.x;
    const int chunk = blockIdx.y;
    const int n = quad_idx[pix];
    const float2 uv = reinterpret_cast<const float2*>(tex_uv)[pix];
    const float u = uv.x * (float)(WT - 1);
    const float v = uv.y * (float)(HT - 1);
    int x0 = (int)floorf(u), y0 = (int)floorf(v);
    x0 = min(max(x0, 0), WT - 2);
    y0 = min(max(y0, 0), HT - 2);
    const float wu = u - (float)x0, wv = v - (float)y0;
    const float w00 = (1.f - wu) * (1.f - wv), w01 = wu * (1.f - wv);
    const float w10 = (1.f - wu) * wv, w11 = wu * wv;
    const int off0 = n * SLAB + y0 * WT + x0, off1 = off0 + WT;
    const float* p = x + (size_t)chunk * 8 * NTEX * SLAB;
    float* o = out + (size_t)chunk * 8 * NPIX + pix;
    #pragma unroll
    for (int ch = 0; ch < 8; ++ch) {
        float2 r0, r1;
        __builtin_memcpy(&r0, p + off0, 8);
        __builtin_memcpy(&r1, p + off1, 8);
        o[0] = w00 * r0.x + w01 * r0.y + w10 * r1.x + w11 * r1.y;
        p += (size_t)NTEX * SLAB;
        o += NPIX;
    }
}

extern "C" void kernel_launch(void* const* d_in, const int* in_sizes, int n_in,
                              void* d_out, int out_size, void* d_ws, size_t ws_size,
                              hipStream_t stream) {
    const float* x        = (const float*)d_in[0];
    const int*   quad_idx = (const int*)d_in[1];
    const float* tex_uv   = (const float*)d_in[2];
    float*       out      = (float*)d_out;
    char* ws = (char*)d_ws;

    if (ws_size >= WS_NEED_BIG) {
        unsigned* base    = (unsigned*)(ws + WS_BASE);
        unsigned* cursor  = (unsigned*)(ws + WS_CURSOR);
        unsigned* rank_of = (unsigned*)(ws + WS_T1);
        uint2*    meta    = (uint2*)(ws + WS_T1 + 4 * (size_t)MB);
        float*    compact = (float*)(ws + WS_T1 + 12 * (size_t)MB);
        unsigned* hist    = (unsigned*)(ws + WS_T1 + 12 * (size_t)MB); // overlay

        (void)hipMemsetAsync(hist, 0, NTEX * 64, stream);
        k_hist<<<NPIX / HB_PIX, 256, 0, stream>>>(quad_idx, hist);
        k_scan<<<1, 512, 0, stream>>>(hist, base, cursor);
        k_meta<<<NPIX / MR_PIX, 256, 0, stream>>>(quad_idx, tex_uv, cursor,
                                                  meta, rank_of);
        k_gather8<<<NTEX * 4, 512, 0, stream>>>(x, base, meta, compact);
        k_scatter32<<<NPIX / 256, 256, 0, stream>>>(rank_of, compact, out);
    } else if (ws_size >= WS_NEED_SMALL) {
        unsigned* base   = (unsigned*)(ws + WS_BASE);
        unsigned* cursor = (unsigned*)(ws + WS_CURSOR);
        uint2*    meta   = (uint2*)(ws + WS_T1);
        unsigned* hist   = (unsigned*)(ws + WS_T1);   // overlay (dead pre-k_meta)

        (void)hipMemsetAsync(hist, 0, NTEX * 64, stream);
        k_hist<<<NPIX / HB_PIX, 256, 0, stream>>>(quad_idx, hist);
        k_scan<<<1, 512, 0, stream>>>(hist, base, cursor);
        k_meta<<<NPIX / MR_PIX, 256, 0, stream>>>(quad_idx, tex_uv, cursor,
                                                  meta, (unsigned*)nullptr);
        k_main<<<NTEX * NCH, 256, 0, stream>>>(x, base, meta, out);
    } else {
        dim3 grid(NPIX / 256, 4);
        k_direct<<<grid, 256, 0, stream>>>(x, quad_idx, tex_uv, out);
    }
}